// Round 2
// baseline (711.171 us; speedup 1.0000x reference)
//
#include <hip/hip_runtime.h>
#include <stdint.h>

#define N_NODES 100000
#define N_EDGES 1600000
#define D_INF   128
#define D_HID   64
#define D_LAT   32
#define NB      98      // ceil(N_NODES/1024)

// ---------------- CSR build ----------------

__global__ void k_zero(int* __restrict__ counts) {
  int i = blockIdx.x * 256 + threadIdx.x;
  if (i < N_NODES) counts[i] = 0;
}

__global__ void k_count(const int* __restrict__ dst, int* __restrict__ counts) {
  int e = blockIdx.x * 256 + threadIdx.x;
  if (e < N_EDGES) atomicAdd(&counts[dst[e]], 1);
}

__global__ void k_blocksum(const int* __restrict__ counts, int* __restrict__ bsums) {
  __shared__ int red[4];
  int base = blockIdx.x * 1024 + threadIdx.x * 4;
  int s = 0;
#pragma unroll
  for (int j = 0; j < 4; j++) { int i = base + j; if (i < N_NODES) s += counts[i]; }
#pragma unroll
  for (int off = 32; off > 0; off >>= 1) s += __shfl_down(s, off, 64);
  if ((threadIdx.x & 63) == 0) red[threadIdx.x >> 6] = s;
  __syncthreads();
  if (threadIdx.x == 0) bsums[blockIdx.x] = red[0] + red[1] + red[2] + red[3];
}

__global__ void k_scanblocks(const int* __restrict__ bsums, int* __restrict__ bbase,
                             int* __restrict__ offsets) {
  __shared__ int sh[128];
  int t = threadIdx.x;
  int v = (t < NB) ? bsums[t] : 0;
  sh[t] = v;
  __syncthreads();
  int incl = v;
#pragma unroll
  for (int off = 1; off < 128; off <<= 1) {
    int x = (t >= off) ? sh[t - off] : 0;
    __syncthreads();
    incl += x;
    sh[t] = incl;
    __syncthreads();
  }
  if (t < NB) bbase[t] = incl - v;
  if (t == NB - 1) offsets[N_NODES] = incl;   // == N_EDGES
}

__global__ void k_scanchunk(const int* __restrict__ counts, const int* __restrict__ bbase,
                            int* __restrict__ offsets, int* __restrict__ cursor,
                            float* __restrict__ dinv) {
  __shared__ int sh[256];
  int b = blockIdx.x, t = threadIdx.x;
  int base = b * 1024 + t * 4;
  int v[4]; int s = 0;
#pragma unroll
  for (int j = 0; j < 4; j++) { v[j] = (base + j < N_NODES) ? counts[base + j] : 0; s += v[j]; }
  sh[t] = s;
  __syncthreads();
  int incl = s;
#pragma unroll
  for (int off = 1; off < 256; off <<= 1) {
    int x = (t >= off) ? sh[t - off] : 0;
    __syncthreads();
    incl += x;
    sh[t] = incl;
    __syncthreads();
  }
  int run = bbase[b] + incl - s;
#pragma unroll
  for (int j = 0; j < 4; j++) {
    int i = base + j;
    if (i < N_NODES) {
      offsets[i] = run;
      cursor[i]  = run;
      dinv[i]    = rsqrtf((float)(v[j] + 1));   // deg = in-count + self-loop, always >= 1
      run += v[j];
    }
  }
}

__global__ void k_build(const int* __restrict__ src, const int* __restrict__ dst,
                        const float* __restrict__ dinv, int* __restrict__ cursor,
                        int* __restrict__ csr_src, float* __restrict__ csr_w) {
  int e = blockIdx.x * 256 + threadIdx.x;
  if (e < N_EDGES) {
    int s = src[e], d = dst[e];
    int slot = atomicAdd(&cursor[d], 1);
    csr_src[slot] = s;
    csr_w[slot]   = dinv[s] * dinv[d];
  }
}

// ---------------- dense transform: Y[N,M] = X[N,K] @ W[K,M] ----------------

template<int K, int M, int NPB>
__global__ void k_gemm(const float* __restrict__ X, const float* __restrict__ W,
                       float* __restrict__ Y) {
  __shared__ float Wl[K * M];
  for (int i = threadIdx.x; i < K * M; i += 256) Wl[i] = W[i];
  __syncthreads();
  int node0 = blockIdx.x * NPB;
#pragma unroll
  for (int idx = threadIdx.x; idx < NPB * M; idx += 256) {
    int n = node0 + idx / M;
    int c = idx % M;
    if (n < N_NODES) {
      const float4* xr = (const float4*)(X + (size_t)n * K);
      float acc = 0.f;
#pragma unroll
      for (int k4 = 0; k4 < K / 4; k4++) {
        float4 xv = xr[k4];
        acc += xv.x * Wl[(4 * k4 + 0) * M + c];
        acc += xv.y * Wl[(4 * k4 + 1) * M + c];
        acc += xv.z * Wl[(4 * k4 + 2) * M + c];
        acc += xv.w * Wl[(4 * k4 + 3) * M + c];
      }
      Y[(size_t)n * M + c] = acc;
    }
  }
}

// ---------------- aggregation (gather side, wave per node) ----------------

template<int FEAT, bool RELU>
__global__ void k_aggregate(const float* __restrict__ H, const int* __restrict__ offsets,
                            const int* __restrict__ csr_src, const float* __restrict__ csr_w,
                            const float* __restrict__ dinv, const float* __restrict__ bias,
                            float* __restrict__ OUT) {
  int node = blockIdx.x * 4 + (threadIdx.x >> 6);
  int lane = threadIdx.x & 63;
  if (node >= N_NODES) return;
  int beg = offsets[node], end = offsets[node + 1];
  float di = dinv[node];

  if constexpr (FEAT == 64) {
    float acc = H[(size_t)node * 64 + lane] * di * di;   // self-loop
    int p = beg;
    for (; p + 1 < end; p += 2) {
      int   s0 = csr_src[p],   s1 = csr_src[p + 1];
      float w0 = csr_w[p],     w1 = csr_w[p + 1];
      float h0 = H[(size_t)s0 * 64 + lane];
      float h1 = H[(size_t)s1 * 64 + lane];
      acc += h0 * w0;
      acc += h1 * w1;
    }
    if (p < end) acc += H[(size_t)csr_src[p] * 64 + lane] * csr_w[p];
    acc += bias[lane];
    if (RELU) acc = fmaxf(acc, 0.f);
    OUT[(size_t)node * 64 + lane] = acc;
  } else {
    int f = lane & 31, half = lane >> 5;
    float acc = (half == 0) ? H[(size_t)node * 32 + f] * di * di : 0.f;
    for (int p = beg + half; p < end; p += 2) {
      acc += H[(size_t)csr_src[p] * 32 + f] * csr_w[p];
    }
    acc += __shfl_down(acc, 32, 64);   // fold upper half into lower
    if (half == 0) {
      acc += bias[f];
      if (RELU) acc = fmaxf(acc, 0.f);
      OUT[(size_t)node * 32 + f] = acc;
    }
  }
}

// ---------------- decoder: h3 = relu(z@Wd1+bd1); recon = h3@Wd2+bd2 ----------------

__global__ void k_decoder(const float* __restrict__ Z, const float* __restrict__ Wd1,
                          const float* __restrict__ bd1, const float* __restrict__ Wd2,
                          const float* __restrict__ bd2, float* __restrict__ RECON) {
  __shared__ float W1l[32 * 64];
  __shared__ float W2l[64 * 128];
  __shared__ float b1l[64];
  __shared__ float b2l[128];
  __shared__ float H3[8 * 64];
  for (int i = threadIdx.x; i < 32 * 64; i += 256) W1l[i] = Wd1[i];
  for (int i = threadIdx.x; i < 64 * 128; i += 256) W2l[i] = Wd2[i];
  if (threadIdx.x < 64) b1l[threadIdx.x] = bd1[threadIdx.x];
  {
    int t2 = (int)threadIdx.x - 64;
    if (t2 >= 0 && t2 < 128) b2l[t2] = bd2[t2];
  }
  __syncthreads();
  int node0 = blockIdx.x * 8;
#pragma unroll
  for (int r = 0; r < 2; r++) {
    int idx = r * 256 + threadIdx.x;
    int n = node0 + idx / 64, c = idx % 64;
    float acc = b1l[c];
    if (n < N_NODES) {
      const float* zr = Z + (size_t)n * 32;
#pragma unroll
      for (int k = 0; k < 32; k++) acc += zr[k] * W1l[k * 64 + c];
    }
    H3[idx] = fmaxf(acc, 0.f);
  }
  __syncthreads();
#pragma unroll
  for (int r = 0; r < 4; r++) {
    int idx = r * 256 + threadIdx.x;
    int n = node0 + idx / 128, c = idx % 128;
    if (n < N_NODES) {
      const float* h3 = &H3[(idx / 128) * 64];
      float acc = b2l[c];
#pragma unroll
      for (int k = 0; k < 64; k++) acc += h3[k] * W2l[k * 128 + c];
      RECON[(size_t)n * 128 + c] = acc;
    }
  }
}

// ---------------- launch ----------------

extern "C" void kernel_launch(void* const* d_in, const int* in_sizes, int n_in,
                              void* d_out, int out_size, void* d_ws, size_t ws_size,
                              hipStream_t stream) {
  const float* x    = (const float*)d_in[0];
  const int*   eidx = (const int*)d_in[1];     // harness passes integers as int32
  const int*   esrc = eidx;                    // edge_index[0]
  const int*   edst = eidx + N_EDGES;          // edge_index[1]
  const float* W1  = (const float*)d_in[2];
  const float* b1  = (const float*)d_in[3];
  const float* W2  = (const float*)d_in[4];
  const float* b2  = (const float*)d_in[5];
  const float* Wd1 = (const float*)d_in[6];
  const float* bd1 = (const float*)d_in[7];
  const float* Wd2 = (const float*)d_in[8];
  const float* bd2 = (const float*)d_in[9];

  float* recon = (float*)d_out;                                  // [N,128]
  float* z     = (float*)d_out + (size_t)N_NODES * D_INF;        // [N,32]
  // Scratch activations parked in the dead recon region (written only by the
  // final decoder kernel): h1 [N,64] at recon+0, z1 [N,64] at recon+N*64.
  // h2 [N,32] reuses h1's region after h1 is dead.
  float* h1 = recon;
  float* z1 = recon + (size_t)N_NODES * 64;
  float* h2 = recon;

  char* ws = (char*)d_ws;
  int*   counts  = (int*)(ws + 0);          //   400,000 B
  int*   offsets = (int*)(ws + 409600);     //   400,004 B
  int*   cursor  = (int*)(ws + 819200);     //   400,000 B
  float* dinv    = (float*)(ws + 1228800);  //   400,000 B
  int*   bsums   = (int*)(ws + 1638400);    //       392 B
  int*   bbase   = (int*)(ws + 1639424);    //       392 B
  int*   csr_src = (int*)(ws + 1640448);    // 6,400,000 B
  float* csr_w   = (float*)(ws + 8040448);  // 6,400,000 B
  // total ws use: 14,440,448 B

  k_zero<<<(N_NODES + 255) / 256, 256, 0, stream>>>(counts);
  k_count<<<(N_EDGES + 255) / 256, 256, 0, stream>>>(edst, counts);
  k_blocksum<<<NB, 256, 0, stream>>>(counts, bsums);
  k_scanblocks<<<1, 128, 0, stream>>>(bsums, bbase, offsets);
  k_scanchunk<<<NB, 256, 0, stream>>>(counts, bbase, offsets, cursor, dinv);
  k_build<<<(N_EDGES + 255) / 256, 256, 0, stream>>>(esrc, edst, dinv, cursor, csr_src, csr_w);

  // h1 = x @ W1
  k_gemm<128, 64, 16><<<(N_NODES + 15) / 16, 256, 0, stream>>>(x, W1, h1);
  // z1 = relu(agg(h1) + b1)
  k_aggregate<64, true><<<(N_NODES + 3) / 4, 256, 0, stream>>>(h1, offsets, csr_src, csr_w, dinv, b1, z1);
  // h2 = z1 @ W2   (writes over h1; h1 dead)
  k_gemm<64, 32, 32><<<(N_NODES + 31) / 32, 256, 0, stream>>>(z1, W2, h2);
  // z = agg(h2) + b2   (latent output)
  k_aggregate<32, false><<<(N_NODES + 3) / 4, 256, 0, stream>>>(h2, offsets, csr_src, csr_w, dinv, b2, z);
  // recon = relu(z@Wd1+bd1) @ Wd2 + bd2   (overwrites h1/z1 scratch)
  k_decoder<<<(N_NODES + 7) / 8, 256, 0, stream>>>(z, Wd1, bd1, Wd2, bd2, recon);
}

// Round 3
// 694.212 us; speedup vs baseline: 1.0244x; 1.0244x over previous
//
#include <hip/hip_runtime.h>
#include <stdint.h>

#define N_NODES 100000
#define N_EDGES 1600000
#define D_INF   128
#define D_HID   64
#define D_LAT   32
#define NB      98      // ceil(N_NODES/1024)

typedef __attribute__((ext_vector_type(8))) short bf16x8;
typedef __attribute__((ext_vector_type(4))) float f32x4;

__device__ __forceinline__ unsigned short f2bf(float v) {
  union { float f; unsigned int u; } x; x.f = v;
  unsigned int u = x.u + 0x7FFF + ((x.u >> 16) & 1);   // RNE
  return (unsigned short)(u >> 16);
}
__device__ __forceinline__ float bf2f(unsigned short h) {
  union { unsigned int u; float f; } x; x.u = ((unsigned int)h) << 16;
  return x.f;
}

// ---------------- CSR build ----------------

__global__ void k_zero(int* __restrict__ counts) {
  int i = blockIdx.x * 256 + threadIdx.x;
  if (i < N_NODES) counts[i] = 0;
}

__global__ void k_count(const int* __restrict__ dst, int* __restrict__ counts) {
  int e = blockIdx.x * 256 + threadIdx.x;
  if (e < N_EDGES) atomicAdd(&counts[dst[e]], 1);
}

__global__ void k_blocksum(const int* __restrict__ counts, int* __restrict__ bsums) {
  __shared__ int red[4];
  int base = blockIdx.x * 1024 + threadIdx.x * 4;
  int s = 0;
#pragma unroll
  for (int j = 0; j < 4; j++) { int i = base + j; if (i < N_NODES) s += counts[i]; }
#pragma unroll
  for (int off = 32; off > 0; off >>= 1) s += __shfl_down(s, off, 64);
  if ((threadIdx.x & 63) == 0) red[threadIdx.x >> 6] = s;
  __syncthreads();
  if (threadIdx.x == 0) bsums[blockIdx.x] = red[0] + red[1] + red[2] + red[3];
}

__global__ void k_scanblocks(const int* __restrict__ bsums, int* __restrict__ bbase,
                             int* __restrict__ offsets) {
  __shared__ int sh[128];
  int t = threadIdx.x;
  int v = (t < NB) ? bsums[t] : 0;
  sh[t] = v;
  __syncthreads();
  int incl = v;
#pragma unroll
  for (int off = 1; off < 128; off <<= 1) {
    int x = (t >= off) ? sh[t - off] : 0;
    __syncthreads();
    incl += x;
    sh[t] = incl;
    __syncthreads();
  }
  if (t < NB) bbase[t] = incl - v;
  if (t == NB - 1) offsets[N_NODES] = incl;   // == N_EDGES
}

__global__ void k_scanchunk(const int* __restrict__ counts, const int* __restrict__ bbase,
                            int* __restrict__ offsets, int* __restrict__ cursor,
                            float* __restrict__ dinv) {
  __shared__ int sh[256];
  int b = blockIdx.x, t = threadIdx.x;
  int base = b * 1024 + t * 4;
  int v[4]; int s = 0;
#pragma unroll
  for (int j = 0; j < 4; j++) { v[j] = (base + j < N_NODES) ? counts[base + j] : 0; s += v[j]; }
  sh[t] = s;
  __syncthreads();
  int incl = s;
#pragma unroll
  for (int off = 1; off < 256; off <<= 1) {
    int x = (t >= off) ? sh[t - off] : 0;
    __syncthreads();
    incl += x;
    sh[t] = incl;
    __syncthreads();
  }
  int run = bbase[b] + incl - s;
#pragma unroll
  for (int j = 0; j < 4; j++) {
    int i = base + j;
    if (i < N_NODES) {
      offsets[i] = run;
      cursor[i]  = run;
      dinv[i]    = rsqrtf((float)(v[j] + 1));   // deg = in-count + self-loop
      run += v[j];
    }
  }
}

__global__ void k_build(const int* __restrict__ src, const int* __restrict__ dst,
                        const float* __restrict__ dinv, int* __restrict__ cursor,
                        int* __restrict__ csr_src, float* __restrict__ csr_w) {
  int e = blockIdx.x * 256 + threadIdx.x;
  if (e < N_EDGES) {
    int s = src[e], d = dst[e];
    int slot = atomicAdd(&cursor[d], 1);
    csr_src[slot] = s;
    csr_w[slot]   = dinv[s] * dinv[d];
  }
}

// ---------------- MFMA GEMM: Y[N,M] = X[N,K] @ W[K,M], fp32 io, bf16x2 split ----------------
// block = 256 threads (4 waves), NODES nodes per block.
// A staged [node][k] bf16 hi/lo, stride KP (pad 8 -> 16B aligned rows, 2-way-free banks).
// B staged transposed [n][k] bf16 hi/lo, same stride.
// mfma_f32_16x16x32_bf16: A-frag A[m=lane&15][k=quad*8+j]; B-frag B[k=quad*8+j][n=lane&15];
// C/D: col=lane&15, row=quad*4+reg  (HW-verified mappings, m89/m120).

template<int NODES, int K, int M>
__global__ __launch_bounds__(256) void k_mfma_gemm(const float* __restrict__ X,
                                                   const float* __restrict__ W,
                                                   float* __restrict__ Y) {
  constexpr int KP     = K + 8;
  constexpr int NSTRIP = M / 16;
  constexpr int KSTEPS = K / 32;
  constexpr int MTW    = (NODES / 16) * NSTRIP / 4;   // output 16x16 cells per wave
  __shared__ unsigned short Ahi[NODES * KP], Alo[NODES * KP];
  __shared__ unsigned short Bhi[M * KP],     Blo[M * KP];

  int t = threadIdx.x;
  int node0 = blockIdx.x * NODES;

  // stage X (float4 coalesced, zero-fill OOB) with hi/lo bf16 split
  for (int i = t; i < NODES * K / 4; i += 256) {
    int n = i / (K / 4), f4 = i % (K / 4);
    float4 v = make_float4(0.f, 0.f, 0.f, 0.f);
    if (node0 + n < N_NODES) v = ((const float4*)(X + (size_t)(node0 + n) * K))[f4];
    int base = n * KP + f4 * 4;
    float vv[4] = {v.x, v.y, v.z, v.w};
#pragma unroll
    for (int j = 0; j < 4; j++) {
      unsigned short h = f2bf(vv[j]);
      Ahi[base + j] = h;
      Alo[base + j] = f2bf(vv[j] - bf2f(h));
    }
  }
  // stage W[K][M] -> Bt[n][k]
  for (int i = t; i < K * M; i += 256) {
    int k = i / M, n = i % M;
    float v = W[i];
    unsigned short h = f2bf(v);
    Bhi[n * KP + k] = h;
    Blo[n * KP + k] = f2bf(v - bf2f(h));
  }
  __syncthreads();

  int w = t >> 6, lane = t & 63;
  int quad = lane >> 4, r16 = lane & 15;
  int strip = w % NSTRIP;

  bf16x8 bh[KSTEPS], bl[KSTEPS];
  {
    const unsigned short* bp = &Bhi[(strip * 16 + r16) * KP + quad * 8];
    const unsigned short* bq = &Blo[(strip * 16 + r16) * KP + quad * 8];
#pragma unroll
    for (int ks = 0; ks < KSTEPS; ks++) {
      bh[ks] = *(const bf16x8*)(bp + ks * 32);
      bl[ks] = *(const bf16x8*)(bq + ks * 32);
    }
  }

#pragma unroll
  for (int c = 0; c < MTW; c++) {
    int mt = (w / NSTRIP) * MTW + c;
    f32x4 acc = {0.f, 0.f, 0.f, 0.f};
    const unsigned short* ap = &Ahi[(mt * 16 + r16) * KP + quad * 8];
    const unsigned short* aq = &Alo[(mt * 16 + r16) * KP + quad * 8];
#pragma unroll
    for (int ks = 0; ks < KSTEPS; ks++) {
      bf16x8 ah = *(const bf16x8*)(ap + ks * 32);
      bf16x8 al = *(const bf16x8*)(aq + ks * 32);
      acc = __builtin_amdgcn_mfma_f32_16x16x32_bf16(ah, bh[ks], acc, 0, 0, 0);
      acc = __builtin_amdgcn_mfma_f32_16x16x32_bf16(ah, bl[ks], acc, 0, 0, 0);
      acc = __builtin_amdgcn_mfma_f32_16x16x32_bf16(al, bh[ks], acc, 0, 0, 0);
    }
    int gn  = node0 + mt * 16 + quad * 4;
    int col = strip * 16 + r16;
#pragma unroll
    for (int r = 0; r < 4; r++) {
      if (gn + r < N_NODES) Y[(size_t)(gn + r) * M + col] = acc[r];
    }
  }
}

// ---------------- aggregation (gather side, wave per node) ----------------

template<int FEAT, bool RELU>
__global__ void k_aggregate(const float* __restrict__ H, const int* __restrict__ offsets,
                            const int* __restrict__ csr_src, const float* __restrict__ csr_w,
                            const float* __restrict__ dinv, const float* __restrict__ bias,
                            float* __restrict__ OUT) {
  int node = blockIdx.x * 4 + (threadIdx.x >> 6);
  int lane = threadIdx.x & 63;
  if (node >= N_NODES) return;
  int beg = offsets[node], end = offsets[node + 1];
  float di = dinv[node];

  if constexpr (FEAT == 64) {
    float acc = H[(size_t)node * 64 + lane] * di * di;   // self-loop
    int p = beg;
    for (; p + 1 < end; p += 2) {
      int   s0 = csr_src[p],   s1 = csr_src[p + 1];
      float w0 = csr_w[p],     w1 = csr_w[p + 1];
      float h0 = H[(size_t)s0 * 64 + lane];
      float h1 = H[(size_t)s1 * 64 + lane];
      acc += h0 * w0;
      acc += h1 * w1;
    }
    if (p < end) acc += H[(size_t)csr_src[p] * 64 + lane] * csr_w[p];
    acc += bias[lane];
    if (RELU) acc = fmaxf(acc, 0.f);
    OUT[(size_t)node * 64 + lane] = acc;
  } else {
    int f = lane & 31, half = lane >> 5;
    float acc = (half == 0) ? H[(size_t)node * 32 + f] * di * di : 0.f;
    for (int p = beg + half; p < end; p += 2) {
      acc += H[(size_t)csr_src[p] * 32 + f] * csr_w[p];
    }
    acc += __shfl_down(acc, 32, 64);   // fold upper half into lower
    if (half == 0) {
      acc += bias[f];
      if (RELU) acc = fmaxf(acc, 0.f);
      OUT[(size_t)node * 32 + f] = acc;
    }
  }
}

// ---------------- decoder: h3 = relu(z@Wd1+bd1); recon = h3@Wd2+bd2 ----------------
// 16 nodes/block; stage2 register-blocks 8 nodes per thread so each W2 LDS read
// feeds 8 FMAs and h3 reads are broadcast float4s.

#define DEC_NPB 16
__global__ __launch_bounds__(256) void k_decoder(const float* __restrict__ Z,
                                                 const float* __restrict__ Wd1,
                                                 const float* __restrict__ bd1,
                                                 const float* __restrict__ Wd2,
                                                 const float* __restrict__ bd2,
                                                 float* __restrict__ RECON) {
  __shared__ float W1l[32 * 64];
  __shared__ float W2l[64 * 128];
  __shared__ float b1l[64];
  __shared__ float b2l[128];
  __shared__ float zl[DEC_NPB * 32];
  __shared__ float h3l[DEC_NPB * 64];
  int t = threadIdx.x;
  for (int i = t; i < 32 * 64; i += 256) W1l[i] = Wd1[i];
  for (int i = t; i < 64 * 128; i += 256) W2l[i] = Wd2[i];
  if (t < 64) b1l[t] = bd1[t];
  if (t >= 64 && t < 192) b2l[t - 64] = bd2[t - 64];
  int node0 = blockIdx.x * DEC_NPB;
  if (t < 128) {
    int n = t / 8, f4 = t % 8;
    float4 v = make_float4(0.f, 0.f, 0.f, 0.f);
    if (node0 + n < N_NODES) v = ((const float4*)(Z + (size_t)(node0 + n) * 32))[f4];
    *(float4*)&zl[n * 32 + f4 * 4] = v;
  }
  __syncthreads();
  // stage 1: h3 = relu(z @ Wd1 + b1)   (16*64 outputs)
#pragma unroll
  for (int r = 0; r < 4; r++) {
    int i = r * 256 + t;
    int n = i >> 6, c = i & 63;
    float acc = b1l[c];
#pragma unroll
    for (int k4 = 0; k4 < 8; k4++) {
      float4 zv = *(float4*)&zl[n * 32 + k4 * 4];
      acc += zv.x * W1l[(4 * k4 + 0) * 64 + c];
      acc += zv.y * W1l[(4 * k4 + 1) * 64 + c];
      acc += zv.z * W1l[(4 * k4 + 2) * 64 + c];
      acc += zv.w * W1l[(4 * k4 + 3) * 64 + c];
    }
    h3l[n * 64 + c] = fmaxf(acc, 0.f);
  }
  __syncthreads();
  // stage 2: recon = h3 @ Wd2 + b2   (thread owns col c and 8 nodes)
  int c = t & 127, ng = t >> 7;
  float acc[8];
#pragma unroll
  for (int j = 0; j < 8; j++) acc[j] = b2l[c];
#pragma unroll
  for (int k4 = 0; k4 < 16; k4++) {
    float w0 = W2l[(4 * k4 + 0) * 128 + c];
    float w1 = W2l[(4 * k4 + 1) * 128 + c];
    float w2 = W2l[(4 * k4 + 2) * 128 + c];
    float w3 = W2l[(4 * k4 + 3) * 128 + c];
#pragma unroll
    for (int j = 0; j < 8; j++) {
      float4 h = *(float4*)&h3l[(ng * 8 + j) * 64 + 4 * k4];
      acc[j] += h.x * w0 + h.y * w1 + h.z * w2 + h.w * w3;
    }
  }
#pragma unroll
  for (int j = 0; j < 8; j++) {
    int n = node0 + ng * 8 + j;
    if (n < N_NODES) RECON[(size_t)n * 128 + c] = acc[j];
  }
}

// ---------------- launch ----------------

extern "C" void kernel_launch(void* const* d_in, const int* in_sizes, int n_in,
                              void* d_out, int out_size, void* d_ws, size_t ws_size,
                              hipStream_t stream) {
  const float* x    = (const float*)d_in[0];
  const int*   eidx = (const int*)d_in[1];     // int32 per harness contract
  const int*   esrc = eidx;                    // edge_index[0]
  const int*   edst = eidx + N_EDGES;          // edge_index[1]
  const float* W1  = (const float*)d_in[2];
  const float* b1  = (const float*)d_in[3];
  const float* W2  = (const float*)d_in[4];
  const float* b2  = (const float*)d_in[5];
  const float* Wd1 = (const float*)d_in[6];
  const float* bd1 = (const float*)d_in[7];
  const float* Wd2 = (const float*)d_in[8];
  const float* bd2 = (const float*)d_in[9];

  float* recon = (float*)d_out;                                  // [N,128]
  float* z     = (float*)d_out + (size_t)N_NODES * D_INF;        // [N,32]
  // Scratch activations in the dead recon region (written only by k_decoder):
  float* h1 = recon;                           // [N,64]
  float* z1 = recon + (size_t)N_NODES * 64;    // [N,64]
  float* h2 = recon;                           // [N,32] (h1 dead by then)

  char* ws = (char*)d_ws;
  int*   counts  = (int*)(ws + 0);
  int*   offsets = (int*)(ws + 409600);
  int*   cursor  = (int*)(ws + 819200);
  float* dinv    = (float*)(ws + 1228800);
  int*   bsums   = (int*)(ws + 1638400);
  int*   bbase   = (int*)(ws + 1639424);
  int*   csr_src = (int*)(ws + 1640448);
  float* csr_w   = (float*)(ws + 8040448);
  // total ws use: 14,440,448 B

  k_zero<<<(N_NODES + 255) / 256, 256, 0, stream>>>(counts);
  k_count<<<(N_EDGES + 255) / 256, 256, 0, stream>>>(edst, counts);
  k_blocksum<<<NB, 256, 0, stream>>>(counts, bsums);
  k_scanblocks<<<1, 128, 0, stream>>>(bsums, bbase, offsets);
  k_scanchunk<<<NB, 256, 0, stream>>>(counts, bbase, offsets, cursor, dinv);
  k_build<<<(N_EDGES + 255) / 256, 256, 0, stream>>>(esrc, edst, dinv, cursor, csr_src, csr_w);

  // h1 = x @ W1   (32 nodes/block; 3125 blocks covers 100000 exactly)
  k_mfma_gemm<32, 128, 64><<<3125, 256, 0, stream>>>(x, W1, h1);
  // z1 = relu(agg(h1) + b1)
  k_aggregate<64, true><<<(N_NODES + 3) / 4, 256, 0, stream>>>(h1, offsets, csr_src, csr_w, dinv, b1, z1);
  // h2 = z1 @ W2
  k_mfma_gemm<64, 64, 32><<<(N_NODES + 63) / 64, 256, 0, stream>>>(z1, W2, h2);
  // z = agg(h2) + b2   (latent output)
  k_aggregate<32, false><<<(N_NODES + 3) / 4, 256, 0, stream>>>(h2, offsets, csr_src, csr_w, dinv, b2, z);
  // recon = relu(z@Wd1+bd1) @ Wd2 + bd2
  k_decoder<<<(N_NODES + DEC_NPB - 1) / DEC_NPB, 256, 0, stream>>>(z, Wd1, bd1, Wd2, bd2, recon);
}

// Round 4
// 541.491 us; speedup vs baseline: 1.3134x; 1.2820x over previous
//
#include <hip/hip_runtime.h>
#include <stdint.h>

#define N_NODES 100000
#define N_EDGES 1600000
#define D_INF   128
#define D_HID   64
#define D_LAT   32
#define NB      98      // ceil(N_NODES/1024)

typedef __attribute__((ext_vector_type(8))) short bf16x8;
typedef __attribute__((ext_vector_type(4))) float f32x4;

__device__ __forceinline__ unsigned short f2bf(float v) {
  union { float f; unsigned int u; } x; x.f = v;
  unsigned int u = x.u + 0x7FFF + ((x.u >> 16) & 1);   // RNE
  return (unsigned short)(u >> 16);
}
__device__ __forceinline__ float bf2f(unsigned short h) {
  union { unsigned int u; float f; } x; x.u = ((unsigned int)h) << 16;
  return x.f;
}

// ---------------- CSR build ----------------

__global__ void k_zero(int* __restrict__ counts) {
  int i = blockIdx.x * 256 + threadIdx.x;
  if (i < N_NODES) counts[i] = 0;
}

__global__ void k_count(const int* __restrict__ dst, int* __restrict__ counts) {
  int e = blockIdx.x * 256 + threadIdx.x;
  if (e < N_EDGES) atomicAdd(&counts[dst[e]], 1);
}

__global__ void k_blocksum(const int* __restrict__ counts, int* __restrict__ bsums) {
  __shared__ int red[4];
  int base = blockIdx.x * 1024 + threadIdx.x * 4;
  int s = 0;
#pragma unroll
  for (int j = 0; j < 4; j++) { int i = base + j; if (i < N_NODES) s += counts[i]; }
#pragma unroll
  for (int off = 32; off > 0; off >>= 1) s += __shfl_down(s, off, 64);
  if ((threadIdx.x & 63) == 0) red[threadIdx.x >> 6] = s;
  __syncthreads();
  if (threadIdx.x == 0) bsums[blockIdx.x] = red[0] + red[1] + red[2] + red[3];
}

__global__ void k_scanblocks(const int* __restrict__ bsums, int* __restrict__ bbase,
                             int* __restrict__ offsets) {
  __shared__ int sh[128];
  int t = threadIdx.x;
  int v = (t < NB) ? bsums[t] : 0;
  sh[t] = v;
  __syncthreads();
  int incl = v;
#pragma unroll
  for (int off = 1; off < 128; off <<= 1) {
    int x = (t >= off) ? sh[t - off] : 0;
    __syncthreads();
    incl += x;
    sh[t] = incl;
    __syncthreads();
  }
  if (t < NB) bbase[t] = incl - v;
  if (t == NB - 1) offsets[N_NODES] = incl;   // == N_EDGES
}

__global__ void k_scanchunk(const int* __restrict__ counts, const int* __restrict__ bbase,
                            int* __restrict__ offsets, int* __restrict__ cursor,
                            float* __restrict__ dinv) {
  __shared__ int sh[256];
  int b = blockIdx.x, t = threadIdx.x;
  int base = b * 1024 + t * 4;
  int v[4]; int s = 0;
#pragma unroll
  for (int j = 0; j < 4; j++) { v[j] = (base + j < N_NODES) ? counts[base + j] : 0; s += v[j]; }
  sh[t] = s;
  __syncthreads();
  int incl = s;
#pragma unroll
  for (int off = 1; off < 256; off <<= 1) {
    int x = (t >= off) ? sh[t - off] : 0;
    __syncthreads();
    incl += x;
    sh[t] = incl;
    __syncthreads();
  }
  int run = bbase[b] + incl - s;
#pragma unroll
  for (int j = 0; j < 4; j++) {
    int i = base + j;
    if (i < N_NODES) {
      offsets[i] = run;
      cursor[i]  = run;
      dinv[i]    = rsqrtf((float)(v[j] + 1));   // deg = in-count + self-loop
      run += v[j];
    }
  }
}

__global__ void k_build(const int* __restrict__ src, const int* __restrict__ dst,
                        const float* __restrict__ dinv, int* __restrict__ cursor,
                        int* __restrict__ csr_src, float* __restrict__ csr_w) {
  int e = blockIdx.x * 256 + threadIdx.x;
  if (e < N_EDGES) {
    int s = src[e], d = dst[e];
    int slot = atomicAdd(&cursor[d], 1);
    csr_src[slot] = s;
    csr_w[slot]   = dinv[s] * dinv[d];
  }
}

// ---------------- weight prep: W[K][M] fp32 -> Bt[col][k] bf16 hi/lo ----------------

__global__ void k_prep_w(const float* __restrict__ W1, const float* __restrict__ W2,
                         const float* __restrict__ Wd1, const float* __restrict__ Wd2,
                         unsigned short* __restrict__ w1hi, unsigned short* __restrict__ w1lo,
                         unsigned short* __restrict__ w2hi, unsigned short* __restrict__ w2lo,
                         unsigned short* __restrict__ wd1hi, unsigned short* __restrict__ wd1lo,
                         unsigned short* __restrict__ wd2hi, unsigned short* __restrict__ wd2lo) {
  const float* src; unsigned short *hi, *lo; int K, M;
  switch (blockIdx.x) {
    case 0:  src = W1;  hi = w1hi;  lo = w1lo;  K = 128; M = 64;  break;
    case 1:  src = W2;  hi = w2hi;  lo = w2lo;  K = 64;  M = 32;  break;
    case 2:  src = Wd1; hi = wd1hi; lo = wd1lo; K = 32;  M = 64;  break;
    default: src = Wd2; hi = wd2hi; lo = wd2lo; K = 64;  M = 128; break;
  }
  int KP = K + 8;
  for (int i = threadIdx.x; i < K * M; i += 256) {
    int k = i / M, c = i % M;
    float v = src[i];
    unsigned short h = f2bf(v);
    hi[c * KP + k] = h;
    lo[c * KP + k] = f2bf(v - bf2f(h));
  }
}

// ---------------- MFMA GEMM: Y[N,M] = X[N,K] @ W[K,M], fp32 io, bf16x2 split ----------------
// A staged in LDS [node][k] hi/lo (KP = K+8: 16B-aligned rows, 2-way-free banks).
// B fragments read directly from pre-transposed global Bt[col][k] (L1/L2-resident).
// mfma_f32_16x16x32_bf16: A[m=lane&15][k=quad*8+j]; B[k=quad*8+j][n=lane&15];
// C/D: col=lane&15, row=quad*4+reg.

template<int NODES, int K, int M>
__global__ __launch_bounds__(256) void k_mfma_gemm(const float* __restrict__ X,
                                                   const unsigned short* __restrict__ Bhi,
                                                   const unsigned short* __restrict__ Blo,
                                                   float* __restrict__ Y) {
  constexpr int KP     = K + 8;
  constexpr int NSTRIP = M / 16;
  constexpr int KSTEPS = K / 32;
  constexpr int MTW    = (NODES / 16) * NSTRIP / 4;
  __shared__ __align__(16) unsigned short Ahi[NODES * KP];
  __shared__ __align__(16) unsigned short Alo[NODES * KP];

  int t = threadIdx.x;
  int node0 = blockIdx.x * NODES;

  for (int i = t; i < NODES * K / 4; i += 256) {
    int n = i / (K / 4), f4 = i % (K / 4);
    float4 v = make_float4(0.f, 0.f, 0.f, 0.f);
    if (node0 + n < N_NODES) v = ((const float4*)(X + (size_t)(node0 + n) * K))[f4];
    int base = n * KP + f4 * 4;
    float vv[4] = {v.x, v.y, v.z, v.w};
#pragma unroll
    for (int j = 0; j < 4; j++) {
      unsigned short h = f2bf(vv[j]);
      Ahi[base + j] = h;
      Alo[base + j] = f2bf(vv[j] - bf2f(h));
    }
  }
  __syncthreads();

  int w = t >> 6, lane = t & 63;
  int quad = lane >> 4, r16 = lane & 15;
  int strip = w % NSTRIP;

  bf16x8 bh[KSTEPS], bl[KSTEPS];
  const unsigned short* bp = Bhi + (strip * 16 + r16) * KP + quad * 8;
  const unsigned short* bq = Blo + (strip * 16 + r16) * KP + quad * 8;
#pragma unroll
  for (int ks = 0; ks < KSTEPS; ks++) {
    bh[ks] = *(const bf16x8*)(bp + ks * 32);
    bl[ks] = *(const bf16x8*)(bq + ks * 32);
  }

#pragma unroll
  for (int c = 0; c < MTW; c++) {
    int mt = (w / NSTRIP) * MTW + c;
    f32x4 acc = {0.f, 0.f, 0.f, 0.f};
    const unsigned short* ap = &Ahi[(mt * 16 + r16) * KP + quad * 8];
    const unsigned short* aq = &Alo[(mt * 16 + r16) * KP + quad * 8];
#pragma unroll
    for (int ks = 0; ks < KSTEPS; ks++) {
      bf16x8 ah = *(const bf16x8*)(ap + ks * 32);
      bf16x8 al = *(const bf16x8*)(aq + ks * 32);
      acc = __builtin_amdgcn_mfma_f32_16x16x32_bf16(ah, bh[ks], acc, 0, 0, 0);
      acc = __builtin_amdgcn_mfma_f32_16x16x32_bf16(ah, bl[ks], acc, 0, 0, 0);
      acc = __builtin_amdgcn_mfma_f32_16x16x32_bf16(al, bh[ks], acc, 0, 0, 0);
    }
    int gn  = node0 + mt * 16 + quad * 4;
    int col = strip * 16 + r16;
#pragma unroll
    for (int r = 0; r < 4; r++) {
      if (gn + r < N_NODES) Y[(size_t)(gn + r) * M + col] = acc[r];
    }
  }
}

// ---------------- aggregation (gather side, wave per node) ----------------

template<int FEAT, bool RELU>
__global__ void k_aggregate(const float* __restrict__ H, const int* __restrict__ offsets,
                            const int* __restrict__ csr_src, const float* __restrict__ csr_w,
                            const float* __restrict__ dinv, const float* __restrict__ bias,
                            float* __restrict__ OUT) {
  int node = blockIdx.x * 4 + (threadIdx.x >> 6);
  int lane = threadIdx.x & 63;
  if (node >= N_NODES) return;
  int beg = offsets[node], end = offsets[node + 1];
  float di = dinv[node];

  if constexpr (FEAT == 64) {
    float acc = H[(size_t)node * 64 + lane] * di * di;   // self-loop
    int p = beg;
    for (; p + 1 < end; p += 2) {
      int   s0 = csr_src[p],   s1 = csr_src[p + 1];
      float w0 = csr_w[p],     w1 = csr_w[p + 1];
      float h0 = H[(size_t)s0 * 64 + lane];
      float h1 = H[(size_t)s1 * 64 + lane];
      acc += h0 * w0;
      acc += h1 * w1;
    }
    if (p < end) acc += H[(size_t)csr_src[p] * 64 + lane] * csr_w[p];
    acc += bias[lane];
    if (RELU) acc = fmaxf(acc, 0.f);
    OUT[(size_t)node * 64 + lane] = acc;
  } else {
    int f = lane & 31, half = lane >> 5;
    float acc = (half == 0) ? H[(size_t)node * 32 + f] * di * di : 0.f;
    for (int p = beg + half; p < end; p += 2) {
      acc += H[(size_t)csr_src[p] * 32 + f] * csr_w[p];
    }
    acc += __shfl_down(acc, 32, 64);   // fold upper half into lower
    if (half == 0) {
      acc += bias[f];
      if (RELU) acc = fmaxf(acc, 0.f);
      OUT[(size_t)node * 32 + f] = acc;
    }
  }
}

// ---------------- decoder: fused 2-stage MFMA ----------------
// 64 nodes/block, 4 waves. Stage1: h3 = relu(z@Wd1+b1) (K=32), h3 -> LDS hi/lo.
// Stage2: recon = h3@Wd2+b2 (K=64). B-frags from pre-transposed global weights.

__global__ __launch_bounds__(256) void k_decoder_mfma(
    const float* __restrict__ Z,
    const unsigned short* __restrict__ B1hi, const unsigned short* __restrict__ B1lo,
    const float* __restrict__ bd1,
    const unsigned short* __restrict__ B2hi, const unsigned short* __restrict__ B2lo,
    const float* __restrict__ bd2, float* __restrict__ RECON) {
  constexpr int KP1 = 40;   // 32+8
  constexpr int KP2 = 72;   // 64+8
  __shared__ __align__(16) unsigned short Azhi[64 * KP1];
  __shared__ __align__(16) unsigned short Azlo[64 * KP1];
  __shared__ __align__(16) unsigned short H3hi[64 * KP2];
  __shared__ __align__(16) unsigned short H3lo[64 * KP2];
  int t = threadIdx.x;
  int node0 = blockIdx.x * 64;

  // stage z [64 x 32] fp32 -> bf16 hi/lo
  for (int i = t; i < 512; i += 256) {
    int n = i >> 3, f4 = i & 7;
    float4 v = make_float4(0.f, 0.f, 0.f, 0.f);
    if (node0 + n < N_NODES) v = ((const float4*)(Z + (size_t)(node0 + n) * 32))[f4];
    int base = n * KP1 + f4 * 4;
    float vv[4] = {v.x, v.y, v.z, v.w};
#pragma unroll
    for (int j = 0; j < 4; j++) {
      unsigned short h = f2bf(vv[j]);
      Azhi[base + j] = h;
      Azlo[base + j] = f2bf(vv[j] - bf2f(h));
    }
  }
  __syncthreads();

  int w = t >> 6, lane = t & 63;
  int quad = lane >> 4, r16 = lane & 15;

  // ---- stage 1: 4x4 cells; wave w owns col-strip w, loops node-tiles m ----
  {
    int col = w * 16 + r16;
    float bias1 = bd1[col];
    bf16x8 bh = *(const bf16x8*)(B1hi + col * KP1 + quad * 8);
    bf16x8 bl = *(const bf16x8*)(B1lo + col * KP1 + quad * 8);
#pragma unroll
    for (int m = 0; m < 4; m++) {
      bf16x8 ah = *(const bf16x8*)(Azhi + (m * 16 + r16) * KP1 + quad * 8);
      bf16x8 al = *(const bf16x8*)(Azlo + (m * 16 + r16) * KP1 + quad * 8);
      f32x4 acc = {0.f, 0.f, 0.f, 0.f};
      acc = __builtin_amdgcn_mfma_f32_16x16x32_bf16(ah, bh, acc, 0, 0, 0);
      acc = __builtin_amdgcn_mfma_f32_16x16x32_bf16(ah, bl, acc, 0, 0, 0);
      acc = __builtin_amdgcn_mfma_f32_16x16x32_bf16(al, bh, acc, 0, 0, 0);
#pragma unroll
      for (int r = 0; r < 4; r++) {
        int row = m * 16 + quad * 4 + r;
        float hv = fmaxf(acc[r] + bias1, 0.f);
        unsigned short h = f2bf(hv);
        H3hi[row * KP2 + col] = h;
        H3lo[row * KP2 + col] = f2bf(hv - bf2f(h));
      }
    }
  }
  __syncthreads();

  // ---- stage 2: 4x8 cells; wave w owns col-strips {w, w+4} ----
#pragma unroll
  for (int sp = 0; sp < 2; sp++) {
    int strip = w + sp * 4;
    int col = strip * 16 + r16;
    float bias2 = bd2[col];
    const unsigned short* b2h = B2hi + col * KP2 + quad * 8;
    const unsigned short* b2l = B2lo + col * KP2 + quad * 8;
    bf16x8 bh0 = *(const bf16x8*)(b2h);
    bf16x8 bh1 = *(const bf16x8*)(b2h + 32);
    bf16x8 bl0 = *(const bf16x8*)(b2l);
    bf16x8 bl1 = *(const bf16x8*)(b2l + 32);
#pragma unroll
    for (int m = 0; m < 4; m++) {
      const unsigned short* ahp = H3hi + (m * 16 + r16) * KP2 + quad * 8;
      const unsigned short* alp = H3lo + (m * 16 + r16) * KP2 + quad * 8;
      bf16x8 ah0 = *(const bf16x8*)(ahp);
      bf16x8 ah1 = *(const bf16x8*)(ahp + 32);
      bf16x8 al0 = *(const bf16x8*)(alp);
      bf16x8 al1 = *(const bf16x8*)(alp + 32);
      f32x4 acc = {0.f, 0.f, 0.f, 0.f};
      acc = __builtin_amdgcn_mfma_f32_16x16x32_bf16(ah0, bh0, acc, 0, 0, 0);
      acc = __builtin_amdgcn_mfma_f32_16x16x32_bf16(ah1, bh1, acc, 0, 0, 0);
      acc = __builtin_amdgcn_mfma_f32_16x16x32_bf16(ah0, bl0, acc, 0, 0, 0);
      acc = __builtin_amdgcn_mfma_f32_16x16x32_bf16(ah1, bl1, acc, 0, 0, 0);
      acc = __builtin_amdgcn_mfma_f32_16x16x32_bf16(al0, bh0, acc, 0, 0, 0);
      acc = __builtin_amdgcn_mfma_f32_16x16x32_bf16(al1, bh1, acc, 0, 0, 0);
#pragma unroll
      for (int r = 0; r < 4; r++) {
        int n = node0 + m * 16 + quad * 4 + r;
        if (n < N_NODES) RECON[(size_t)n * 128 + col] = acc[r] + bias2;
      }
    }
  }
}

// ---------------- launch ----------------

extern "C" void kernel_launch(void* const* d_in, const int* in_sizes, int n_in,
                              void* d_out, int out_size, void* d_ws, size_t ws_size,
                              hipStream_t stream) {
  const float* x    = (const float*)d_in[0];
  const int*   eidx = (const int*)d_in[1];     // int32 per harness contract
  const int*   esrc = eidx;                    // edge_index[0]
  const int*   edst = eidx + N_EDGES;          // edge_index[1]
  const float* W1  = (const float*)d_in[2];
  const float* b1  = (const float*)d_in[3];
  const float* W2  = (const float*)d_in[4];
  const float* b2  = (const float*)d_in[5];
  const float* Wd1 = (const float*)d_in[6];
  const float* bd1 = (const float*)d_in[7];
  const float* Wd2 = (const float*)d_in[8];
  const float* bd2 = (const float*)d_in[9];

  float* recon = (float*)d_out;                                  // [N,128]
  float* z     = (float*)d_out + (size_t)N_NODES * D_INF;        // [N,32]
  // Scratch activations in the dead recon region (written only by k_decoder_mfma):
  float* h1 = recon;                           // [N,64]
  float* z1 = recon + (size_t)N_NODES * 64;    // [N,64]
  float* h2 = recon;                           // [N,32] (h1 dead by then)

  char* ws = (char*)d_ws;
  int*   counts  = (int*)(ws + 0);
  int*   offsets = (int*)(ws + 409600);
  int*   cursor  = (int*)(ws + 819200);
  float* dinv    = (float*)(ws + 1228800);
  int*   bsums   = (int*)(ws + 1638400);
  int*   bbase   = (int*)(ws + 1639424);
  int*   csr_src = (int*)(ws + 1640448);
  float* csr_w   = (float*)(ws + 8040448);
  // pre-transposed bf16 hi/lo weights (16B-aligned offsets)
  unsigned short* w1hi  = (unsigned short*)(ws + 14440448);  // 64*136*2  = 17408
  unsigned short* w1lo  = (unsigned short*)(ws + 14457856);
  unsigned short* w2hi  = (unsigned short*)(ws + 14475264);  // 32*72*2   = 4608
  unsigned short* w2lo  = (unsigned short*)(ws + 14479872);
  unsigned short* wd1hi = (unsigned short*)(ws + 14484480);  // 64*40*2   = 5120
  unsigned short* wd1lo = (unsigned short*)(ws + 14489600);
  unsigned short* wd2hi = (unsigned short*)(ws + 14494720);  // 128*72*2  = 18432
  unsigned short* wd2lo = (unsigned short*)(ws + 14513152);
  // total ws use: 14,531,584 B

  k_zero<<<(N_NODES + 255) / 256, 256, 0, stream>>>(counts);
  k_count<<<(N_EDGES + 255) / 256, 256, 0, stream>>>(edst, counts);
  k_blocksum<<<NB, 256, 0, stream>>>(counts, bsums);
  k_scanblocks<<<1, 128, 0, stream>>>(bsums, bbase, offsets);
  k_scanchunk<<<NB, 256, 0, stream>>>(counts, bbase, offsets, cursor, dinv);
  k_build<<<(N_EDGES + 255) / 256, 256, 0, stream>>>(esrc, edst, dinv, cursor, csr_src, csr_w);
  k_prep_w<<<4, 256, 0, stream>>>(W1, W2, Wd1, Wd2, w1hi, w1lo, w2hi, w2lo,
                                  wd1hi, wd1lo, wd2hi, wd2lo);

  // h1 = x @ W1
  k_mfma_gemm<64, 128, 64><<<(N_NODES + 63) / 64, 256, 0, stream>>>(x, w1hi, w1lo, h1);
  // z1 = relu(agg(h1) + b1)
  k_aggregate<64, true><<<(N_NODES + 3) / 4, 256, 0, stream>>>(h1, offsets, csr_src, csr_w, dinv, b1, z1);
  // h2 = z1 @ W2
  k_mfma_gemm<64, 64, 32><<<(N_NODES + 63) / 64, 256, 0, stream>>>(z1, w2hi, w2lo, h2);
  // z = agg(h2) + b2   (latent output)
  k_aggregate<32, false><<<(N_NODES + 3) / 4, 256, 0, stream>>>(h2, offsets, csr_src, csr_w, dinv, b2, z);
  // recon = relu(z@Wd1+bd1) @ Wd2 + bd2
  k_decoder_mfma<<<(N_NODES + 63) / 64, 256, 0, stream>>>(z, wd1hi, wd1lo, bd1,
                                                          wd2hi, wd2lo, bd2, recon);
}

// Round 5
// 511.348 us; speedup vs baseline: 1.3908x; 1.0589x over previous
//
#include <hip/hip_runtime.h>
#include <stdint.h>

#define N_NODES 100000
#define N_EDGES 1600000
#define D_INF   128
#define D_HID   64
#define D_LAT   32
#define NB      98      // ceil(N_NODES/1024)

typedef __attribute__((ext_vector_type(8))) short bf16x8;
typedef __attribute__((ext_vector_type(4))) float f32x4;

__device__ __forceinline__ unsigned short f2bf(float v) {
  union { float f; unsigned int u; } x; x.f = v;
  unsigned int u = x.u + 0x7FFF + ((x.u >> 16) & 1);   // RNE
  return (unsigned short)(u >> 16);
}
__device__ __forceinline__ float bf2f(unsigned short h) {
  union { unsigned int u; float f; } x; x.u = ((unsigned int)h) << 16;
  return x.f;
}

// ---------------- CSR build ----------------

__global__ void k_zero(int* __restrict__ counts) {
  int i = blockIdx.x * 256 + threadIdx.x;
  if (i < N_NODES) counts[i] = 0;
}

__global__ void k_count(const int* __restrict__ dst, int* __restrict__ counts) {
  int e = blockIdx.x * 256 + threadIdx.x;
  if (e < N_EDGES) atomicAdd(&counts[dst[e]], 1);
}

__global__ void k_blocksum(const int* __restrict__ counts, int* __restrict__ bsums) {
  __shared__ int red[4];
  int base = blockIdx.x * 1024 + threadIdx.x * 4;
  int s = 0;
#pragma unroll
  for (int j = 0; j < 4; j++) { int i = base + j; if (i < N_NODES) s += counts[i]; }
#pragma unroll
  for (int off = 32; off > 0; off >>= 1) s += __shfl_down(s, off, 64);
  if ((threadIdx.x & 63) == 0) red[threadIdx.x >> 6] = s;
  __syncthreads();
  if (threadIdx.x == 0) bsums[blockIdx.x] = red[0] + red[1] + red[2] + red[3];
}

__global__ void k_scanblocks(const int* __restrict__ bsums, int* __restrict__ bbase,
                             int* __restrict__ offsets) {
  __shared__ int sh[128];
  int t = threadIdx.x;
  int v = (t < NB) ? bsums[t] : 0;
  sh[t] = v;
  __syncthreads();
  int incl = v;
#pragma unroll
  for (int off = 1; off < 128; off <<= 1) {
    int x = (t >= off) ? sh[t - off] : 0;
    __syncthreads();
    incl += x;
    sh[t] = incl;
    __syncthreads();
  }
  if (t < NB) bbase[t] = incl - v;
  if (t == NB - 1) offsets[N_NODES] = incl;   // == N_EDGES
}

__global__ void k_scanchunk(const int* __restrict__ counts, const int* __restrict__ bbase,
                            int* __restrict__ offsets, int* __restrict__ cursor,
                            float* __restrict__ dinv) {
  __shared__ int sh[256];
  int b = blockIdx.x, t = threadIdx.x;
  int base = b * 1024 + t * 4;
  int v[4]; int s = 0;
#pragma unroll
  for (int j = 0; j < 4; j++) { v[j] = (base + j < N_NODES) ? counts[base + j] : 0; s += v[j]; }
  sh[t] = s;
  __syncthreads();
  int incl = s;
#pragma unroll
  for (int off = 1; off < 256; off <<= 1) {
    int x = (t >= off) ? sh[t - off] : 0;
    __syncthreads();
    incl += x;
    sh[t] = incl;
    __syncthreads();
  }
  int run = bbase[b] + incl - s;
#pragma unroll
  for (int j = 0; j < 4; j++) {
    int i = base + j;
    if (i < N_NODES) {
      offsets[i] = run;
      cursor[i]  = run;
      dinv[i]    = rsqrtf((float)(v[j] + 1));   // deg = in-count + self-loop
      run += v[j];
    }
  }
}

// Partitioned CSR build: part p keeps only dst in [p*12500, (p+1)*12500), so each
// block's scattered (src,w) int2 stores land in a 1.6 MB csr8 slice (one XCD L2)
// -> write lines accumulate fully before eviction (round 4: 155 MB HBM writes
// for 12.8 MB payload). Edge list re-read 8x coalesced (102 MB, cheap).
#define BUILD_PARTS 8
#define NODES_PER_PART 12500
#define BUILD_CHUNKS 391   // ceil(400000 int4s / 1024)

__global__ __launch_bounds__(256) void k_build(const int* __restrict__ esrc,
                                               const int* __restrict__ edst,
                                               const float* __restrict__ dinv,
                                               int* __restrict__ cursor,
                                               int2* __restrict__ csr8) {
  int part  = blockIdx.x & (BUILD_PARTS - 1);   // round-robins over XCDs
  int chunk = blockIdx.x >> 3;
  int lo = part * NODES_PER_PART, hi = lo + NODES_PER_PART;
  const int4* s4 = (const int4*)esrc;
  const int4* d4 = (const int4*)edst;
#pragma unroll
  for (int i = 0; i < 4; i++) {
    int idx4 = chunk * 1024 + i * 256 + threadIdx.x;
    if (idx4 < N_EDGES / 4) {
      int4 ss = s4[idx4];
      int4 dd = d4[idx4];
      int sa[4] = {ss.x, ss.y, ss.z, ss.w};
      int da[4] = {dd.x, dd.y, dd.z, dd.w};
#pragma unroll
      for (int j = 0; j < 4; j++) {
        int d = da[j];
        if (d >= lo && d < hi) {
          int s = sa[j];
          int slot = atomicAdd(&cursor[d], 1);
          csr8[slot] = make_int2(s, __float_as_int(dinv[s] * dinv[d]));
        }
      }
    }
  }
}

// ---------------- weight prep: W[K][M] fp32 -> Bt[col][k] bf16 hi/lo ----------------

__global__ void k_prep_w(const float* __restrict__ W1, const float* __restrict__ W2,
                         const float* __restrict__ Wd1, const float* __restrict__ Wd2,
                         unsigned short* __restrict__ w1hi, unsigned short* __restrict__ w1lo,
                         unsigned short* __restrict__ w2hi, unsigned short* __restrict__ w2lo,
                         unsigned short* __restrict__ wd1hi, unsigned short* __restrict__ wd1lo,
                         unsigned short* __restrict__ wd2hi, unsigned short* __restrict__ wd2lo) {
  const float* src; unsigned short *hi, *lo; int K, M;
  switch (blockIdx.x) {
    case 0:  src = W1;  hi = w1hi;  lo = w1lo;  K = 128; M = 64;  break;
    case 1:  src = W2;  hi = w2hi;  lo = w2lo;  K = 64;  M = 32;  break;
    case 2:  src = Wd1; hi = wd1hi; lo = wd1lo; K = 32;  M = 64;  break;
    default: src = Wd2; hi = wd2hi; lo = wd2lo; K = 64;  M = 128; break;
  }
  int KP = K + 8;
  for (int i = threadIdx.x; i < K * M; i += 256) {
    int k = i / M, c = i % M;
    float v = src[i];
    unsigned short h = f2bf(v);
    hi[c * KP + k] = h;
    lo[c * KP + k] = f2bf(v - bf2f(h));
  }
}

// ---------------- MFMA GEMM: Y[N,M] = X[N,K] @ W[K,M], fp32 io, bf16x2 split ----------------

template<int NODES, int K, int M>
__global__ __launch_bounds__(256) void k_mfma_gemm(const float* __restrict__ X,
                                                   const unsigned short* __restrict__ Bhi,
                                                   const unsigned short* __restrict__ Blo,
                                                   float* __restrict__ Y) {
  constexpr int KP     = K + 8;
  constexpr int NSTRIP = M / 16;
  constexpr int KSTEPS = K / 32;
  constexpr int MTW    = (NODES / 16) * NSTRIP / 4;
  __shared__ __align__(16) unsigned short Ahi[NODES * KP];
  __shared__ __align__(16) unsigned short Alo[NODES * KP];

  int t = threadIdx.x;
  int node0 = blockIdx.x * NODES;

  for (int i = t; i < NODES * K / 4; i += 256) {
    int n = i / (K / 4), f4 = i % (K / 4);
    float4 v = make_float4(0.f, 0.f, 0.f, 0.f);
    if (node0 + n < N_NODES) v = ((const float4*)(X + (size_t)(node0 + n) * K))[f4];
    int base = n * KP + f4 * 4;
    float vv[4] = {v.x, v.y, v.z, v.w};
#pragma unroll
    for (int j = 0; j < 4; j++) {
      unsigned short h = f2bf(vv[j]);
      Ahi[base + j] = h;
      Alo[base + j] = f2bf(vv[j] - bf2f(h));
    }
  }
  __syncthreads();

  int w = t >> 6, lane = t & 63;
  int quad = lane >> 4, r16 = lane & 15;
  int strip = w % NSTRIP;

  bf16x8 bh[KSTEPS], bl[KSTEPS];
  const unsigned short* bp = Bhi + (strip * 16 + r16) * KP + quad * 8;
  const unsigned short* bq = Blo + (strip * 16 + r16) * KP + quad * 8;
#pragma unroll
  for (int ks = 0; ks < KSTEPS; ks++) {
    bh[ks] = *(const bf16x8*)(bp + ks * 32);
    bl[ks] = *(const bf16x8*)(bq + ks * 32);
  }

#pragma unroll
  for (int c = 0; c < MTW; c++) {
    int mt = (w / NSTRIP) * MTW + c;
    f32x4 acc = {0.f, 0.f, 0.f, 0.f};
    const unsigned short* ap = &Ahi[(mt * 16 + r16) * KP + quad * 8];
    const unsigned short* aq = &Alo[(mt * 16 + r16) * KP + quad * 8];
#pragma unroll
    for (int ks = 0; ks < KSTEPS; ks++) {
      bf16x8 ah = *(const bf16x8*)(ap + ks * 32);
      bf16x8 al = *(const bf16x8*)(aq + ks * 32);
      acc = __builtin_amdgcn_mfma_f32_16x16x32_bf16(ah, bh[ks], acc, 0, 0, 0);
      acc = __builtin_amdgcn_mfma_f32_16x16x32_bf16(ah, bl[ks], acc, 0, 0, 0);
      acc = __builtin_amdgcn_mfma_f32_16x16x32_bf16(al, bh[ks], acc, 0, 0, 0);
    }
    int gn  = node0 + mt * 16 + quad * 4;
    int col = strip * 16 + r16;
#pragma unroll
    for (int r = 0; r < 4; r++) {
      if (gn + r < N_NODES) Y[(size_t)(gn + r) * M + col] = acc[r];
    }
  }
}

// ---------------- aggregation (gather side, wave per node) ----------------

template<int FEAT, bool RELU>
__global__ void k_aggregate(const float* __restrict__ H, const int* __restrict__ offsets,
                            const int2* __restrict__ csr8,
                            const float* __restrict__ dinv, const float* __restrict__ bias,
                            float* __restrict__ OUT) {
  int node = blockIdx.x * 4 + (threadIdx.x >> 6);
  int lane = threadIdx.x & 63;
  if (node >= N_NODES) return;
  int beg = offsets[node], end = offsets[node + 1];
  float di = dinv[node];

  if constexpr (FEAT == 64) {
    float acc = H[(size_t)node * 64 + lane] * di * di;   // self-loop
    int p = beg;
    for (; p + 1 < end; p += 2) {
      int2 e0 = csr8[p], e1 = csr8[p + 1];
      float h0 = H[(size_t)e0.x * 64 + lane];
      float h1 = H[(size_t)e1.x * 64 + lane];
      acc += h0 * __int_as_float(e0.y);
      acc += h1 * __int_as_float(e1.y);
    }
    if (p < end) {
      int2 e = csr8[p];
      acc += H[(size_t)e.x * 64 + lane] * __int_as_float(e.y);
    }
    acc += bias[lane];
    if (RELU) acc = fmaxf(acc, 0.f);
    OUT[(size_t)node * 64 + lane] = acc;
  } else {
    int f = lane & 31, half = lane >> 5;
    float acc = (half == 0) ? H[(size_t)node * 32 + f] * di * di : 0.f;
    for (int p = beg + half; p < end; p += 2) {
      int2 e = csr8[p];
      acc += H[(size_t)e.x * 32 + f] * __int_as_float(e.y);
    }
    acc += __shfl_down(acc, 32, 64);   // fold upper half into lower
    if (half == 0) {
      acc += bias[f];
      if (RELU) acc = fmaxf(acc, 0.f);
      OUT[(size_t)node * 32 + f] = acc;
    }
  }
}

// ---------------- decoder: fused 2-stage MFMA ----------------

__global__ __launch_bounds__(256) void k_decoder_mfma(
    const float* __restrict__ Z,
    const unsigned short* __restrict__ B1hi, const unsigned short* __restrict__ B1lo,
    const float* __restrict__ bd1,
    const unsigned short* __restrict__ B2hi, const unsigned short* __restrict__ B2lo,
    const float* __restrict__ bd2, float* __restrict__ RECON) {
  constexpr int KP1 = 40;   // 32+8
  constexpr int KP2 = 72;   // 64+8
  __shared__ __align__(16) unsigned short Azhi[64 * KP1];
  __shared__ __align__(16) unsigned short Azlo[64 * KP1];
  __shared__ __align__(16) unsigned short H3hi[64 * KP2];
  __shared__ __align__(16) unsigned short H3lo[64 * KP2];
  int t = threadIdx.x;
  int node0 = blockIdx.x * 64;

  for (int i = t; i < 512; i += 256) {
    int n = i >> 3, f4 = i & 7;
    float4 v = make_float4(0.f, 0.f, 0.f, 0.f);
    if (node0 + n < N_NODES) v = ((const float4*)(Z + (size_t)(node0 + n) * 32))[f4];
    int base = n * KP1 + f4 * 4;
    float vv[4] = {v.x, v.y, v.z, v.w};
#pragma unroll
    for (int j = 0; j < 4; j++) {
      unsigned short h = f2bf(vv[j]);
      Azhi[base + j] = h;
      Azlo[base + j] = f2bf(vv[j] - bf2f(h));
    }
  }
  __syncthreads();

  int w = t >> 6, lane = t & 63;
  int quad = lane >> 4, r16 = lane & 15;

  {
    int col = w * 16 + r16;
    float bias1 = bd1[col];
    bf16x8 bh = *(const bf16x8*)(B1hi + col * KP1 + quad * 8);
    bf16x8 bl = *(const bf16x8*)(B1lo + col * KP1 + quad * 8);
#pragma unroll
    for (int m = 0; m < 4; m++) {
      bf16x8 ah = *(const bf16x8*)(Azhi + (m * 16 + r16) * KP1 + quad * 8);
      bf16x8 al = *(const bf16x8*)(Azlo + (m * 16 + r16) * KP1 + quad * 8);
      f32x4 acc = {0.f, 0.f, 0.f, 0.f};
      acc = __builtin_amdgcn_mfma_f32_16x16x32_bf16(ah, bh, acc, 0, 0, 0);
      acc = __builtin_amdgcn_mfma_f32_16x16x32_bf16(ah, bl, acc, 0, 0, 0);
      acc = __builtin_amdgcn_mfma_f32_16x16x32_bf16(al, bh, acc, 0, 0, 0);
#pragma unroll
      for (int r = 0; r < 4; r++) {
        int row = m * 16 + quad * 4 + r;
        float hv = fmaxf(acc[r] + bias1, 0.f);
        unsigned short h = f2bf(hv);
        H3hi[row * KP2 + col] = h;
        H3lo[row * KP2 + col] = f2bf(hv - bf2f(h));
      }
    }
  }
  __syncthreads();

#pragma unroll
  for (int sp = 0; sp < 2; sp++) {
    int strip = w + sp * 4;
    int col = strip * 16 + r16;
    float bias2 = bd2[col];
    const unsigned short* b2h = B2hi + col * KP2 + quad * 8;
    const unsigned short* b2l = B2lo + col * KP2 + quad * 8;
    bf16x8 bh0 = *(const bf16x8*)(b2h);
    bf16x8 bh1 = *(const bf16x8*)(b2h + 32);
    bf16x8 bl0 = *(const bf16x8*)(b2l);
    bf16x8 bl1 = *(const bf16x8*)(b2l + 32);
#pragma unroll
    for (int m = 0; m < 4; m++) {
      const unsigned short* ahp = H3hi + (m * 16 + r16) * KP2 + quad * 8;
      const unsigned short* alp = H3lo + (m * 16 + r16) * KP2 + quad * 8;
      bf16x8 ah0 = *(const bf16x8*)(ahp);
      bf16x8 ah1 = *(const bf16x8*)(ahp + 32);
      bf16x8 al0 = *(const bf16x8*)(alp);
      bf16x8 al1 = *(const bf16x8*)(alp + 32);
      f32x4 acc = {0.f, 0.f, 0.f, 0.f};
      acc = __builtin_amdgcn_mfma_f32_16x16x32_bf16(ah0, bh0, acc, 0, 0, 0);
      acc = __builtin_amdgcn_mfma_f32_16x16x32_bf16(ah1, bh1, acc, 0, 0, 0);
      acc = __builtin_amdgcn_mfma_f32_16x16x32_bf16(ah0, bl0, acc, 0, 0, 0);
      acc = __builtin_amdgcn_mfma_f32_16x16x32_bf16(ah1, bl1, acc, 0, 0, 0);
      acc = __builtin_amdgcn_mfma_f32_16x16x32_bf16(al0, bh0, acc, 0, 0, 0);
      acc = __builtin_amdgcn_mfma_f32_16x16x32_bf16(al1, bh1, acc, 0, 0, 0);
#pragma unroll
      for (int r = 0; r < 4; r++) {
        int n = node0 + m * 16 + quad * 4 + r;
        if (n < N_NODES) RECON[(size_t)n * 128 + col] = acc[r] + bias2;
      }
    }
  }
}

// ---------------- launch ----------------

extern "C" void kernel_launch(void* const* d_in, const int* in_sizes, int n_in,
                              void* d_out, int out_size, void* d_ws, size_t ws_size,
                              hipStream_t stream) {
  const float* x    = (const float*)d_in[0];
  const int*   eidx = (const int*)d_in[1];     // int32 per harness contract
  const int*   esrc = eidx;                    // edge_index[0]
  const int*   edst = eidx + N_EDGES;          // edge_index[1]
  const float* W1  = (const float*)d_in[2];
  const float* b1  = (const float*)d_in[3];
  const float* W2  = (const float*)d_in[4];
  const float* b2  = (const float*)d_in[5];
  const float* Wd1 = (const float*)d_in[6];
  const float* bd1 = (const float*)d_in[7];
  const float* Wd2 = (const float*)d_in[8];
  const float* bd2 = (const float*)d_in[9];

  float* recon = (float*)d_out;                                  // [N,128]
  float* z     = (float*)d_out + (size_t)N_NODES * D_INF;        // [N,32]
  float* h1 = recon;                           // [N,64]  (dead recon region)
  float* z1 = recon + (size_t)N_NODES * 64;    // [N,64]
  float* h2 = recon;                           // [N,32]  (h1 dead by then)

  char* ws = (char*)d_ws;
  int*   counts  = (int*)(ws + 0);
  int*   offsets = (int*)(ws + 409600);
  int*   cursor  = (int*)(ws + 819200);
  float* dinv    = (float*)(ws + 1228800);
  int*   bsums   = (int*)(ws + 1638400);
  int*   bbase   = (int*)(ws + 1639424);
  int2*  csr8    = (int2*)(ws + 1640448);      // 12,800,000 B packed (src,w)
  unsigned short* w1hi  = (unsigned short*)(ws + 14440448);
  unsigned short* w1lo  = (unsigned short*)(ws + 14457856);
  unsigned short* w2hi  = (unsigned short*)(ws + 14475264);
  unsigned short* w2lo  = (unsigned short*)(ws + 14479872);
  unsigned short* wd1hi = (unsigned short*)(ws + 14484480);
  unsigned short* wd1lo = (unsigned short*)(ws + 14489600);
  unsigned short* wd2hi = (unsigned short*)(ws + 14494720);
  unsigned short* wd2lo = (unsigned short*)(ws + 14513152);
  // total ws use: 14,531,584 B

  k_zero<<<(N_NODES + 255) / 256, 256, 0, stream>>>(counts);
  k_count<<<(N_EDGES + 255) / 256, 256, 0, stream>>>(edst, counts);
  k_blocksum<<<NB, 256, 0, stream>>>(counts, bsums);
  k_scanblocks<<<1, 128, 0, stream>>>(bsums, bbase, offsets);
  k_scanchunk<<<NB, 256, 0, stream>>>(counts, bbase, offsets, cursor, dinv);
  k_build<<<BUILD_CHUNKS * BUILD_PARTS, 256, 0, stream>>>(esrc, edst, dinv, cursor, csr8);
  k_prep_w<<<4, 256, 0, stream>>>(W1, W2, Wd1, Wd2, w1hi, w1lo, w2hi, w2lo,
                                  wd1hi, wd1lo, wd2hi, wd2lo);

  // h1 = x @ W1
  k_mfma_gemm<64, 128, 64><<<(N_NODES + 63) / 64, 256, 0, stream>>>(x, w1hi, w1lo, h1);
  // z1 = relu(agg(h1) + b1)
  k_aggregate<64, true><<<(N_NODES + 3) / 4, 256, 0, stream>>>(h1, offsets, csr8, dinv, b1, z1);
  // h2 = z1 @ W2
  k_mfma_gemm<64, 64, 32><<<(N_NODES + 63) / 64, 256, 0, stream>>>(z1, w2hi, w2lo, h2);
  // z = agg(h2) + b2   (latent output)
  k_aggregate<32, false><<<(N_NODES + 3) / 4, 256, 0, stream>>>(h2, offsets, csr8, dinv, b2, z);
  // recon = relu(z@Wd1+bd1) @ Wd2 + bd2
  k_decoder_mfma<<<(N_NODES + 63) / 64, 256, 0, stream>>>(z, wd1hi, wd1lo, bd1,
                                                          wd2hi, wd2lo, bd2, recon);
}

// Round 6
// 476.021 us; speedup vs baseline: 1.4940x; 1.0742x over previous
//
#include <hip/hip_runtime.h>
#include <stdint.h>

#define N_NODES 100000
#define N_EDGES 1600000
#define D_INF   128
#define D_HID   64
#define D_LAT   32
#define NB      98      // ceil(N_NODES/1024)

typedef __attribute__((ext_vector_type(8))) short bf16x8;
typedef __attribute__((ext_vector_type(4))) float f32x4;

__device__ __forceinline__ unsigned short f2bf(float v) {
  union { float f; unsigned int u; } x; x.f = v;
  unsigned int u = x.u + 0x7FFF + ((x.u >> 16) & 1);   // RNE
  return (unsigned short)(u >> 16);
}
__device__ __forceinline__ float bf2f(unsigned short h) {
  union { unsigned int u; float f; } x; x.u = ((unsigned int)h) << 16;
  return x.f;
}

// ---------------- CSR build ----------------

__global__ void k_zero(int* __restrict__ counts) {
  int i = blockIdx.x * 256 + threadIdx.x;
  if (i < N_NODES) counts[i] = 0;
}

__global__ void k_count(const int* __restrict__ dst, int* __restrict__ counts) {
  int e = blockIdx.x * 256 + threadIdx.x;
  if (e < N_EDGES) atomicAdd(&counts[dst[e]], 1);
}

__global__ void k_blocksum(const int* __restrict__ counts, int* __restrict__ bsums) {
  __shared__ int red[4];
  int base = blockIdx.x * 1024 + threadIdx.x * 4;
  int s = 0;
#pragma unroll
  for (int j = 0; j < 4; j++) { int i = base + j; if (i < N_NODES) s += counts[i]; }
#pragma unroll
  for (int off = 32; off > 0; off >>= 1) s += __shfl_down(s, off, 64);
  if ((threadIdx.x & 63) == 0) red[threadIdx.x >> 6] = s;
  __syncthreads();
  if (threadIdx.x == 0) bsums[blockIdx.x] = red[0] + red[1] + red[2] + red[3];
}

__global__ void k_scanblocks(const int* __restrict__ bsums, int* __restrict__ bbase,
                             int* __restrict__ offsets) {
  __shared__ int sh[128];
  int t = threadIdx.x;
  int v = (t < NB) ? bsums[t] : 0;
  sh[t] = v;
  __syncthreads();
  int incl = v;
#pragma unroll
  for (int off = 1; off < 128; off <<= 1) {
    int x = (t >= off) ? sh[t - off] : 0;
    __syncthreads();
    incl += x;
    sh[t] = incl;
    __syncthreads();
  }
  if (t < NB) bbase[t] = incl - v;
  if (t == NB - 1) offsets[N_NODES] = incl;   // == N_EDGES
}

__global__ void k_scanchunk(const int* __restrict__ counts, const int* __restrict__ bbase,
                            int* __restrict__ offsets, int* __restrict__ cursor,
                            float* __restrict__ dinv) {
  __shared__ int sh[256];
  int b = blockIdx.x, t = threadIdx.x;
  int base = b * 1024 + t * 4;
  int v[4]; int s = 0;
#pragma unroll
  for (int j = 0; j < 4; j++) { v[j] = (base + j < N_NODES) ? counts[base + j] : 0; s += v[j]; }
  sh[t] = s;
  __syncthreads();
  int incl = s;
#pragma unroll
  for (int off = 1; off < 256; off <<= 1) {
    int x = (t >= off) ? sh[t - off] : 0;
    __syncthreads();
    incl += x;
    sh[t] = incl;
    __syncthreads();
  }
  int run = bbase[b] + incl - s;
#pragma unroll
  for (int j = 0; j < 4; j++) {
    int i = base + j;
    if (i < N_NODES) {
      offsets[i] = run;
      cursor[i]  = run;
      dinv[i]    = rsqrtf((float)(v[j] + 1));   // deg = in-count + self-loop
      run += v[j];
    }
  }
}

// Partitioned CSR build (round 5): writes confined to 1.6 MB csr8 slices.
#define BUILD_PARTS 8
#define NODES_PER_PART 12500
#define BUILD_CHUNKS 391   // ceil(400000 int4s / 1024)

__global__ __launch_bounds__(256) void k_build(const int* __restrict__ esrc,
                                               const int* __restrict__ edst,
                                               const float* __restrict__ dinv,
                                               int* __restrict__ cursor,
                                               int2* __restrict__ csr8) {
  int part  = blockIdx.x & (BUILD_PARTS - 1);   // round-robins over XCDs
  int chunk = blockIdx.x >> 3;
  int lo = part * NODES_PER_PART, hi = lo + NODES_PER_PART;
  const int4* s4 = (const int4*)esrc;
  const int4* d4 = (const int4*)edst;
#pragma unroll
  for (int i = 0; i < 4; i++) {
    int idx4 = chunk * 1024 + i * 256 + threadIdx.x;
    if (idx4 < N_EDGES / 4) {
      int4 ss = s4[idx4];
      int4 dd = d4[idx4];
      int sa[4] = {ss.x, ss.y, ss.z, ss.w};
      int da[4] = {dd.x, dd.y, dd.z, dd.w};
#pragma unroll
      for (int j = 0; j < 4; j++) {
        int d = da[j];
        if (d >= lo && d < hi) {
          int s = sa[j];
          int slot = atomicAdd(&cursor[d], 1);
          csr8[slot] = make_int2(s, __float_as_int(dinv[s] * dinv[d]));
        }
      }
    }
  }
}

// ---------------- weight prep: W[K][M] fp32 -> Bt[col][k] bf16 hi/lo ----------------

__global__ void k_prep_w(const float* __restrict__ W1, const float* __restrict__ W2,
                         const float* __restrict__ Wd1, const float* __restrict__ Wd2,
                         unsigned short* __restrict__ w1hi, unsigned short* __restrict__ w1lo,
                         unsigned short* __restrict__ w2hi, unsigned short* __restrict__ w2lo,
                         unsigned short* __restrict__ wd1hi, unsigned short* __restrict__ wd1lo,
                         unsigned short* __restrict__ wd2hi, unsigned short* __restrict__ wd2lo) {
  const float* src; unsigned short *hi, *lo; int K, M;
  switch (blockIdx.x) {
    case 0:  src = W1;  hi = w1hi;  lo = w1lo;  K = 128; M = 64;  break;
    case 1:  src = W2;  hi = w2hi;  lo = w2lo;  K = 64;  M = 32;  break;
    case 2:  src = Wd1; hi = wd1hi; lo = wd1lo; K = 32;  M = 64;  break;
    default: src = Wd2; hi = wd2hi; lo = wd2lo; K = 64;  M = 128; break;
  }
  int KP = K + 8;
  for (int i = threadIdx.x; i < K * M; i += 256) {
    int k = i / M, c = i % M;
    float v = src[i];
    unsigned short h = f2bf(v);
    hi[c * KP + k] = h;
    lo[c * KP + k] = f2bf(v - bf2f(h));
  }
}

// ---------------- MFMA GEMM: Y[N,M] = X[N,K] @ W[K,M], fp32 in, bf16 out ----------------
// Output stored as bf16 (the aggregate gathers it; halves gather traffic).

template<int NODES, int K, int M>
__global__ __launch_bounds__(256) void k_mfma_gemm(const float* __restrict__ X,
                                                   const unsigned short* __restrict__ Bhi,
                                                   const unsigned short* __restrict__ Blo,
                                                   unsigned short* __restrict__ Y16) {
  constexpr int KP     = K + 8;
  constexpr int NSTRIP = M / 16;
  constexpr int KSTEPS = K / 32;
  constexpr int MTW    = (NODES / 16) * NSTRIP / 4;
  __shared__ __align__(16) unsigned short Ahi[NODES * KP];
  __shared__ __align__(16) unsigned short Alo[NODES * KP];

  int t = threadIdx.x;
  int node0 = blockIdx.x * NODES;

  for (int i = t; i < NODES * K / 4; i += 256) {
    int n = i / (K / 4), f4 = i % (K / 4);
    float4 v = make_float4(0.f, 0.f, 0.f, 0.f);
    if (node0 + n < N_NODES) v = ((const float4*)(X + (size_t)(node0 + n) * K))[f4];
    int base = n * KP + f4 * 4;
    float vv[4] = {v.x, v.y, v.z, v.w};
#pragma unroll
    for (int j = 0; j < 4; j++) {
      unsigned short h = f2bf(vv[j]);
      Ahi[base + j] = h;
      Alo[base + j] = f2bf(vv[j] - bf2f(h));
    }
  }
  __syncthreads();

  int w = t >> 6, lane = t & 63;
  int quad = lane >> 4, r16 = lane & 15;
  int strip = w % NSTRIP;

  bf16x8 bh[KSTEPS], bl[KSTEPS];
  const unsigned short* bp = Bhi + (strip * 16 + r16) * KP + quad * 8;
  const unsigned short* bq = Blo + (strip * 16 + r16) * KP + quad * 8;
#pragma unroll
  for (int ks = 0; ks < KSTEPS; ks++) {
    bh[ks] = *(const bf16x8*)(bp + ks * 32);
    bl[ks] = *(const bf16x8*)(bq + ks * 32);
  }

#pragma unroll
  for (int c = 0; c < MTW; c++) {
    int mt = (w / NSTRIP) * MTW + c;
    f32x4 acc = {0.f, 0.f, 0.f, 0.f};
    const unsigned short* ap = &Ahi[(mt * 16 + r16) * KP + quad * 8];
    const unsigned short* aq = &Alo[(mt * 16 + r16) * KP + quad * 8];
#pragma unroll
    for (int ks = 0; ks < KSTEPS; ks++) {
      bf16x8 ah = *(const bf16x8*)(ap + ks * 32);
      bf16x8 al = *(const bf16x8*)(aq + ks * 32);
      acc = __builtin_amdgcn_mfma_f32_16x16x32_bf16(ah, bh[ks], acc, 0, 0, 0);
      acc = __builtin_amdgcn_mfma_f32_16x16x32_bf16(ah, bl[ks], acc, 0, 0, 0);
      acc = __builtin_amdgcn_mfma_f32_16x16x32_bf16(al, bh[ks], acc, 0, 0, 0);
    }
    int gn  = node0 + mt * 16 + quad * 4;
    int col = strip * 16 + r16;
#pragma unroll
    for (int r = 0; r < 4; r++) {
      if (gn + r < N_NODES) Y16[(size_t)(gn + r) * M + col] = f2bf(acc[r]);
    }
  }
}

// ---------------- aggregation (gather side, wave per node, bf16 table) ----------------

template<int FEAT, bool RELU>
__global__ void k_aggregate(const unsigned short* __restrict__ H16,
                            const int* __restrict__ offsets,
                            const int2* __restrict__ csr8,
                            const float* __restrict__ dinv, const float* __restrict__ bias,
                            float* __restrict__ OUT) {
  int node = blockIdx.x * 4 + (threadIdx.x >> 6);
  int lane = threadIdx.x & 63;
  if (node >= N_NODES) return;
  int beg = offsets[node], end = offsets[node + 1];
  float di = dinv[node];

  if constexpr (FEAT == 64) {
    float acc = bf2f(H16[(size_t)node * 64 + lane]) * di * di;   // self-loop
    int p = beg;
    for (; p + 3 < end; p += 4) {
      int2 e0 = csr8[p], e1 = csr8[p + 1], e2 = csr8[p + 2], e3 = csr8[p + 3];
      float h0 = bf2f(H16[(size_t)e0.x * 64 + lane]);
      float h1 = bf2f(H16[(size_t)e1.x * 64 + lane]);
      float h2 = bf2f(H16[(size_t)e2.x * 64 + lane]);
      float h3 = bf2f(H16[(size_t)e3.x * 64 + lane]);
      acc += h0 * __int_as_float(e0.y);
      acc += h1 * __int_as_float(e1.y);
      acc += h2 * __int_as_float(e2.y);
      acc += h3 * __int_as_float(e3.y);
    }
    for (; p < end; p++) {
      int2 e = csr8[p];
      acc += bf2f(H16[(size_t)e.x * 64 + lane]) * __int_as_float(e.y);
    }
    acc += bias[lane];
    if (RELU) acc = fmaxf(acc, 0.f);
    OUT[(size_t)node * 64 + lane] = acc;
  } else {
    int f = lane & 31, half = lane >> 5;
    float acc = (half == 0) ? bf2f(H16[(size_t)node * 32 + f]) * di * di : 0.f;
    int p = beg + half;
    for (; p + 1 < end; p += 4) {
      int2 e0 = csr8[p], e1 = csr8[p + 2 <= end - 1 ? p + 2 : p];
      bool has1 = (p + 2 < end);
      float h0 = bf2f(H16[(size_t)e0.x * 32 + f]);
      acc += h0 * __int_as_float(e0.y);
      if (has1) acc += bf2f(H16[(size_t)e1.x * 32 + f]) * __int_as_float(e1.y);
    }
    if (p < end) {
      int2 e = csr8[p];
      acc += bf2f(H16[(size_t)e.x * 32 + f]) * __int_as_float(e.y);
    }
    acc += __shfl_down(acc, 32, 64);   // fold upper half into lower
    if (half == 0) {
      acc += bias[f];
      if (RELU) acc = fmaxf(acc, 0.f);
      OUT[(size_t)node * 32 + f] = acc;
    }
  }
}

// ---------------- decoder: fused 2-stage MFMA ----------------

__global__ __launch_bounds__(256) void k_decoder_mfma(
    const float* __restrict__ Z,
    const unsigned short* __restrict__ B1hi, const unsigned short* __restrict__ B1lo,
    const float* __restrict__ bd1,
    const unsigned short* __restrict__ B2hi, const unsigned short* __restrict__ B2lo,
    const float* __restrict__ bd2, float* __restrict__ RECON) {
  constexpr int KP1 = 40;   // 32+8
  constexpr int KP2 = 72;   // 64+8
  __shared__ __align__(16) unsigned short Azhi[64 * KP1];
  __shared__ __align__(16) unsigned short Azlo[64 * KP1];
  __shared__ __align__(16) unsigned short H3hi[64 * KP2];
  __shared__ __align__(16) unsigned short H3lo[64 * KP2];
  int t = threadIdx.x;
  int node0 = blockIdx.x * 64;

  for (int i = t; i < 512; i += 256) {
    int n = i >> 3, f4 = i & 7;
    float4 v = make_float4(0.f, 0.f, 0.f, 0.f);
    if (node0 + n < N_NODES) v = ((const float4*)(Z + (size_t)(node0 + n) * 32))[f4];
    int base = n * KP1 + f4 * 4;
    float vv[4] = {v.x, v.y, v.z, v.w};
#pragma unroll
    for (int j = 0; j < 4; j++) {
      unsigned short h = f2bf(vv[j]);
      Azhi[base + j] = h;
      Azlo[base + j] = f2bf(vv[j] - bf2f(h));
    }
  }
  __syncthreads();

  int w = t >> 6, lane = t & 63;
  int quad = lane >> 4, r16 = lane & 15;

  {
    int col = w * 16 + r16;
    float bias1 = bd1[col];
    bf16x8 bh = *(const bf16x8*)(B1hi + col * KP1 + quad * 8);
    bf16x8 bl = *(const bf16x8*)(B1lo + col * KP1 + quad * 8);
#pragma unroll
    for (int m = 0; m < 4; m++) {
      bf16x8 ah = *(const bf16x8*)(Azhi + (m * 16 + r16) * KP1 + quad * 8);
      bf16x8 al = *(const bf16x8*)(Azlo + (m * 16 + r16) * KP1 + quad * 8);
      f32x4 acc = {0.f, 0.f, 0.f, 0.f};
      acc = __builtin_amdgcn_mfma_f32_16x16x32_bf16(ah, bh, acc, 0, 0, 0);
      acc = __builtin_amdgcn_mfma_f32_16x16x32_bf16(ah, bl, acc, 0, 0, 0);
      acc = __builtin_amdgcn_mfma_f32_16x16x32_bf16(al, bh, acc, 0, 0, 0);
#pragma unroll
      for (int r = 0; r < 4; r++) {
        int row = m * 16 + quad * 4 + r;
        float hv = fmaxf(acc[r] + bias1, 0.f);
        unsigned short h = f2bf(hv);
        H3hi[row * KP2 + col] = h;
        H3lo[row * KP2 + col] = f2bf(hv - bf2f(h));
      }
    }
  }
  __syncthreads();

#pragma unroll
  for (int sp = 0; sp < 2; sp++) {
    int strip = w + sp * 4;
    int col = strip * 16 + r16;
    float bias2 = bd2[col];
    const unsigned short* b2h = B2hi + col * KP2 + quad * 8;
    const unsigned short* b2l = B2lo + col * KP2 + quad * 8;
    bf16x8 bh0 = *(const bf16x8*)(b2h);
    bf16x8 bh1 = *(const bf16x8*)(b2h + 32);
    bf16x8 bl0 = *(const bf16x8*)(b2l);
    bf16x8 bl1 = *(const bf16x8*)(b2l + 32);
#pragma unroll
    for (int m = 0; m < 4; m++) {
      const unsigned short* ahp = H3hi + (m * 16 + r16) * KP2 + quad * 8;
      const unsigned short* alp = H3lo + (m * 16 + r16) * KP2 + quad * 8;
      bf16x8 ah0 = *(const bf16x8*)(ahp);
      bf16x8 ah1 = *(const bf16x8*)(ahp + 32);
      bf16x8 al0 = *(const bf16x8*)(alp);
      bf16x8 al1 = *(const bf16x8*)(alp + 32);
      f32x4 acc = {0.f, 0.f, 0.f, 0.f};
      acc = __builtin_amdgcn_mfma_f32_16x16x32_bf16(ah0, bh0, acc, 0, 0, 0);
      acc = __builtin_amdgcn_mfma_f32_16x16x32_bf16(ah1, bh1, acc, 0, 0, 0);
      acc = __builtin_amdgcn_mfma_f32_16x16x32_bf16(ah0, bl0, acc, 0, 0, 0);
      acc = __builtin_amdgcn_mfma_f32_16x16x32_bf16(ah1, bl1, acc, 0, 0, 0);
      acc = __builtin_amdgcn_mfma_f32_16x16x32_bf16(al0, bh0, acc, 0, 0, 0);
      acc = __builtin_amdgcn_mfma_f32_16x16x32_bf16(al1, bh1, acc, 0, 0, 0);
#pragma unroll
      for (int r = 0; r < 4; r++) {
        int n = node0 + m * 16 + quad * 4 + r;
        if (n < N_NODES) RECON[(size_t)n * 128 + col] = acc[r] + bias2;
      }
    }
  }
}

// ---------------- launch ----------------

extern "C" void kernel_launch(void* const* d_in, const int* in_sizes, int n_in,
                              void* d_out, int out_size, void* d_ws, size_t ws_size,
                              hipStream_t stream) {
  const float* x    = (const float*)d_in[0];
  const int*   eidx = (const int*)d_in[1];     // int32 per harness contract
  const int*   esrc = eidx;                    // edge_index[0]
  const int*   edst = eidx + N_EDGES;          // edge_index[1]
  const float* W1  = (const float*)d_in[2];
  const float* b1  = (const float*)d_in[3];
  const float* W2  = (const float*)d_in[4];
  const float* b2  = (const float*)d_in[5];
  const float* Wd1 = (const float*)d_in[6];
  const float* bd1 = (const float*)d_in[7];
  const float* Wd2 = (const float*)d_in[8];
  const float* bd2 = (const float*)d_in[9];

  float* recon = (float*)d_out;                                  // [N,128]
  float* z     = (float*)d_out + (size_t)N_NODES * D_INF;        // [N,32]
  // Scratch in the dead recon region (51.2 MB, written only by k_decoder_mfma):
  //   h1_16 [N,64] bf16 @ +0         (12.8 MB)
  //   z1    [N,64] fp32 @ +12.8 MB   (25.6 MB)
  //   h2_16 [N,32] bf16 @ +38.4 MB   ( 6.4 MB)   -> total 44.8 MB < 51.2 MB
  unsigned short* h1_16 = (unsigned short*)recon;
  float*          z1    = (float*)((char*)recon + 12800000);
  unsigned short* h2_16 = (unsigned short*)((char*)recon + 38400000);

  char* ws = (char*)d_ws;
  int*   counts  = (int*)(ws + 0);
  int*   offsets = (int*)(ws + 409600);
  int*   cursor  = (int*)(ws + 819200);
  float* dinv    = (float*)(ws + 1228800);
  int*   bsums   = (int*)(ws + 1638400);
  int*   bbase   = (int*)(ws + 1639424);
  int2*  csr8    = (int2*)(ws + 1640448);      // 12,800,000 B packed (src,w)
  unsigned short* w1hi  = (unsigned short*)(ws + 14440448);
  unsigned short* w1lo  = (unsigned short*)(ws + 14457856);
  unsigned short* w2hi  = (unsigned short*)(ws + 14475264);
  unsigned short* w2lo  = (unsigned short*)(ws + 14479872);
  unsigned short* wd1hi = (unsigned short*)(ws + 14484480);
  unsigned short* wd1lo = (unsigned short*)(ws + 14489600);
  unsigned short* wd2hi = (unsigned short*)(ws + 14494720);
  unsigned short* wd2lo = (unsigned short*)(ws + 14513152);
  // total ws use: 14,531,584 B

  k_zero<<<(N_NODES + 255) / 256, 256, 0, stream>>>(counts);
  k_count<<<(N_EDGES + 255) / 256, 256, 0, stream>>>(edst, counts);
  k_blocksum<<<NB, 256, 0, stream>>>(counts, bsums);
  k_scanblocks<<<1, 128, 0, stream>>>(bsums, bbase, offsets);
  k_scanchunk<<<NB, 256, 0, stream>>>(counts, bbase, offsets, cursor, dinv);
  k_build<<<BUILD_CHUNKS * BUILD_PARTS, 256, 0, stream>>>(esrc, edst, dinv, cursor, csr8);
  k_prep_w<<<4, 256, 0, stream>>>(W1, W2, Wd1, Wd2, w1hi, w1lo, w2hi, w2lo,
                                  wd1hi, wd1lo, wd2hi, wd2lo);

  // h1 = x @ W1  (bf16 out)
  k_mfma_gemm<64, 128, 64><<<(N_NODES + 63) / 64, 256, 0, stream>>>(x, w1hi, w1lo, h1_16);
  // z1 = relu(agg(h1) + b1)  (fp32 out)
  k_aggregate<64, true><<<(N_NODES + 3) / 4, 256, 0, stream>>>(h1_16, offsets, csr8, dinv, b1, z1);
  // h2 = z1 @ W2  (bf16 out)
  k_mfma_gemm<64, 64, 32><<<(N_NODES + 63) / 64, 256, 0, stream>>>(z1, w2hi, w2lo, h2_16);
  // z = agg(h2) + b2  (latent output, fp32)
  k_aggregate<32, false><<<(N_NODES + 3) / 4, 256, 0, stream>>>(h2_16, offsets, csr8, dinv, b2, z);
  // recon = relu(z@Wd1+bd1) @ Wd2 + bd2
  k_decoder_mfma<<<(N_NODES + 63) / 64, 256, 0, stream>>>(z, wd1hi, wd1lo, bd1,
                                                          wd2hi, wd2lo, bd2, recon);
}